// Round 4
// baseline (308.785 us; speedup 1.0000x reference)
//
#include <hip/hip_runtime.h>
#include <math.h>

#define NB 64
#define NC 512
#define NHW 4096
#define NHID 32
#define NPLANES (NB * NC)          // 32768 planes of 4096 floats
#define CHB 16                     // samples per chunk (16 x 8 MiB = 128 MiB, half of L3)
#define NCHUNK (NB / CHB)          // 4
#define CHPLANES (CHB * NC)        // 8192 planes per chunk

typedef float f32x4 __attribute__((ext_vector_type(4)));

// ---------------- Kernel 1: global average pool (one chunk) ----------------
// Wave-per-plane; normal loads so the chunk allocates in L2/L3.
__global__ __launch_bounds__(256) void pool_kernel(const float* __restrict__ x,
                                                   float* __restrict__ y, int p0) {
    const int wid   = threadIdx.x >> 6;
    const int lane  = threadIdx.x & 63;
    const int plane = p0 + blockIdx.x * 4 + wid;
    const f32x4* __restrict__ xin =
        reinterpret_cast<const f32x4*>(x + (size_t)plane * NHW);

    float s = 0.f;
#pragma unroll
    for (int i = 0; i < 16; ++i) {
        f32x4 v = xin[lane + i * 64];
        s += v.x + v.y + v.z + v.w;
    }
#pragma unroll
    for (int o = 32; o; o >>= 1) s += __shfl_down(s, o, 64);
    if (lane == 0) y[plane] = s * (1.0f / NHW);
}

// ---------------- Kernel 2: routed 2-layer MLP -> sigmoid gate (one chunk) ----
__global__ __launch_bounds__(256) void gate_kernel(const float* __restrict__ y,
                                                   const int* __restrict__ dataset,
                                                   const float* __restrict__ W1,
                                                   const float* __restrict__ W2,
                                                   float* __restrict__ gate, int b0) {
    const int b = b0 + blockIdx.x;
    const int tid = threadIdx.x;

    __shared__ float ys[NC];
    __shared__ float hs[NHID];

    ys[tid]       = y[b * NC + tid];
    ys[tid + 256] = y[b * NC + tid + 256];
    const int e = dataset[b];
    __syncthreads();

    const int hid = tid >> 3;
    const int j   = tid & 7;
    const float* __restrict__ w1row = W1 + ((size_t)e * NHID + hid) * NC;
    float acc = 0.f;
    for (int c = j; c < NC; c += 8) acc += ys[c] * w1row[c];
#pragma unroll
    for (int o = 4; o; o >>= 1) acc += __shfl_down(acc, o, 8);
    if (j == 0) hs[hid] = fmaxf(acc, 0.f);
    __syncthreads();

    const float* __restrict__ w2base = W2 + (size_t)e * NC * NHID;
#pragma unroll
    for (int k = 0; k < 2; ++k) {
        const int c = tid + k * 256;
        const float* __restrict__ w2row = w2base + c * NHID;
        float z = 0.f;
#pragma unroll
        for (int hh = 0; hh < NHID; ++hh) z += hs[hh] * w2row[hh];
        gate[b * NC + c] = 1.0f / (1.0f + expf(-z));
    }
}

// ---------------- Kernel 3: out = x * gate[b,c] (one chunk) ----------------
// Reads the chunk the immediately-preceding pool kernel just pulled into
// L2/L3 (expected hits). Non-temporal stores so the output stream does not
// evict the chunk mid-kernel.
__global__ __launch_bounds__(256) void scale_kernel(const float* __restrict__ x,
                                                    const float* __restrict__ gate,
                                                    float* __restrict__ out, int p0) {
    const int pair = p0 / 2 + blockIdx.x;
    const int pl0 = pair * 2;
    const float g0 = gate[pl0];
    const float g1 = gate[pl0 + 1];
    const size_t base = (size_t)pair * 2048;             // float4 units
    const f32x4* __restrict__ xin = reinterpret_cast<const f32x4*>(x);
    f32x4* __restrict__ o4 = reinterpret_cast<f32x4*>(out);
    const int t = threadIdx.x;

#pragma unroll
    for (int k = 0; k < 4; ++k) {
        const size_t i = base + (size_t)k * 256 + t;
        f32x4 v = xin[i];
        v *= g0;
        __builtin_nontemporal_store(v, &o4[i]);
    }
#pragma unroll
    for (int k = 0; k < 4; ++k) {
        const size_t i = base + 1024 + (size_t)k * 256 + t;
        f32x4 v = xin[i];
        v *= g1;
        __builtin_nontemporal_store(v, &o4[i]);
    }
}

extern "C" void kernel_launch(void* const* d_in, const int* in_sizes, int n_in,
                              void* d_out, int out_size, void* d_ws, size_t ws_size,
                              hipStream_t stream) {
    const float* x       = (const float*)d_in[0];
    const int*   dataset = (const int*)d_in[1];
    const float* W1      = (const float*)d_in[2];
    const float* W2      = (const float*)d_in[3];
    float* out = (float*)d_out;

    float* y    = (float*)d_ws;          // NB*NC floats
    float* gate = y + NB * NC;           // NB*NC floats

    for (int c = 0; c < NCHUNK; ++c) {
        const int b0 = c * CHB;
        const int p0 = b0 * NC;
        pool_kernel <<<CHPLANES / 4, 256, 0, stream>>>(x, y, p0);
        gate_kernel <<<CHB,          256, 0, stream>>>(y, dataset, W1, W2, gate, b0);
        scale_kernel<<<CHPLANES / 2, 256, 0, stream>>>(x, gate, out, p0);
    }
}